// Round 1
// baseline (245.284 us; speedup 1.0000x reference)
//
#include <hip/hip_runtime.h>
#include <hip/hip_bf16.h>

// LengthRegulator: xs [B=32, T=512, D=384] f32, durations [B=32, T=512] i32 in [0,8)
// out [B, T_out=4096, D] f32: each phoneme row repeated `duration` times, left-
// aligned, zero-padded to T_out.
//
// Memory-bound: 201 MB write + ~25 MB read -> ~36 us roofline at 6.3 TB/s.

#define B   32
#define T   512
#define D   384
#define TOUT 4096           // T * DUR_MAX
#define CH  (D / 4)         // 96 float4 chunks per frame
#define F   64              // output frames per expand block

// ---------- kernel 1: grand total of durations -> flag = (total == 0) ----------
__global__ __launch_bounds__(256) void k_total(const int* __restrict__ dur,
                                               int* __restrict__ flag) {
    __shared__ int ssum[4];
    int tid = threadIdx.x;
    int sum = 0;
    for (int i = tid; i < B * T; i += 256) sum += dur[i];
    #pragma unroll
    for (int o = 32; o > 0; o >>= 1) sum += __shfl_down(sum, o);
    if ((tid & 63) == 0) ssum[tid >> 6] = sum;
    __syncthreads();
    if (tid == 0) {
        int tot = ssum[0] + ssum[1] + ssum[2] + ssum[3];
        flag[0] = (tot == 0) ? 1 : 0;
    }
}

// ---------- kernel 2: per-row inclusive scan of durations -> cum[B][T] ----------
__global__ __launch_bounds__(512) void k_scan(const int* __restrict__ dur,
                                              const int* __restrict__ flag,
                                              int* __restrict__ cum) {
    __shared__ int s[T];
    int b = blockIdx.x, t = threadIdx.x;
    int d = dur[b * T + t];
    if (flag[0]) d = 1;      // torch edge case: all-zero durations -> all 1s
    s[t] = d;
    __syncthreads();
    // Hillis-Steele inclusive scan over 512 elements
    #pragma unroll
    for (int off = 1; off < T; off <<= 1) {
        int v = (t >= off) ? s[t - off] : 0;
        __syncthreads();
        s[t] += v;
        __syncthreads();
    }
    cum[b * T + t] = s[t];
}

// ---------- kernel 3: expansion ----------
// grid = (TOUT/F, B), block = 256. One block: batch b, frames [frame0, frame0+F).
__global__ __launch_bounds__(256) void k_expand(const float4* __restrict__ xs4,
                                                const int* __restrict__ cum,
                                                float4* __restrict__ out4) {
    __shared__ int s_cum[T];
    __shared__ int s_idx[F];     // phoneme index per frame, or -1 for pad
    const int b = blockIdx.y;
    const int frame0 = blockIdx.x * F;
    const int tid = threadIdx.x;

    for (int i = tid; i < T; i += 256) s_cum[i] = cum[b * T + i];
    __syncthreads();

    const int last = s_cum[T - 1];
    if (tid < F) {
        int t = frame0 + tid;
        // branchless upper_bound: idx = #elements <= t  (searchsorted side='right')
        int idx = 0;
        #pragma unroll
        for (int step = T / 2; step > 0; step >>= 1)
            if (s_cum[idx + step - 1] <= t) idx += step;
        if (idx > T - 1) idx = T - 1;          // clamp for safe gather
        s_idx[tid] = (t < last) ? idx : -1;    // valid = t < cum[-1]
    }
    __syncthreads();

    // copy F*CH float4 items; item order == contiguous output addresses (coalesced)
    #pragma unroll 4
    for (int item = tid; item < F * CH; item += 256) {
        int f = item / CH;
        int c = item - f * CH;
        int j = s_idx[f];
        float4 v = make_float4(0.f, 0.f, 0.f, 0.f);
        if (j >= 0) v = xs4[(b * T + j) * CH + c];
        out4[((size_t)b * TOUT + frame0 + f) * CH + c] = v;
    }
}

extern "C" void kernel_launch(void* const* d_in, const int* in_sizes, int n_in,
                              void* d_out, int out_size, void* d_ws, size_t ws_size,
                              hipStream_t stream) {
    const float* xs  = (const float*)d_in[0];
    const int*   dur = (const int*)d_in[1];
    float*       out = (float*)d_out;

    // workspace layout: [0] flag (int), [64 B ...] cum[B*T] ints
    int* flag = (int*)d_ws;
    int* cum  = (int*)((char*)d_ws + 64);

    k_total<<<1, 256, 0, stream>>>(dur, flag);
    k_scan<<<B, T, 0, stream>>>(dur, flag, cum);
    dim3 grid(TOUT / F, B);
    k_expand<<<grid, 256, 0, stream>>>((const float4*)xs, cum, (float4*)out);
}

// Round 2
// 228.193 us; speedup vs baseline: 1.0749x; 1.0749x over previous
//
#include <hip/hip_runtime.h>
#include <hip/hip_bf16.h>

// LengthRegulator, single fused kernel.
// xs [B=32, T=512, D=384] f32, durations [B=32, T=512] i32 in [0,8)
// out [B, T_out=4096, D] f32: phoneme rows repeated `duration` times,
// left-aligned, zero-padded to T_out.
//
// Memory-bound: 201 MB write + ~25 MB read -> ~36 us roofline at 6.3 TB/s.
// Each block recomputes its row's cumsum in LDS (cheap, L2-hot) so there is
// exactly ONE dispatch: no helper-kernel serialization, no global cum buffer.

#define B    32
#define T    512
#define D    384
#define TOUT 4096           // T * DUR_MAX
#define CH   (D / 4)        // 96 float4 chunks per frame
#define F    128            // output frames per block
#define NT   512            // threads per block

__global__ __launch_bounds__(NT) void k_lenreg(const float4* __restrict__ xs4,
                                               const int* __restrict__ dur,
                                               float4* __restrict__ out4) {
    __shared__ int s_cum[T];
    __shared__ int s_idx[F];      // phoneme index per frame, or -1 for pad
    __shared__ int s_red[NT / 64];
    const int b      = blockIdx.y;
    const int frame0 = blockIdx.x * F;
    const int tid    = threadIdx.x;

    // ---- load this row's durations and scan (inclusive) in LDS ----
    s_cum[tid] = dur[b * T + tid];
    __syncthreads();
    #pragma unroll
    for (int off = 1; off < T; off <<= 1) {
        int v = (tid >= off) ? s_cum[tid - off] : 0;
        __syncthreads();
        s_cum[tid] += v;
        __syncthreads();
    }

    // ---- rare path: row total == 0 -> need global total for torch edge case ----
    // (if ALL durations in the whole batch are zero, every d becomes 1)
    if (s_cum[T - 1] == 0) {            // wave-uniform branch
        int sum = 0;
        for (int i = tid; i < B * T; i += NT) sum += dur[i];
        #pragma unroll
        for (int o = 32; o > 0; o >>= 1) sum += __shfl_down(sum, o);
        if ((tid & 63) == 0) s_red[tid >> 6] = sum;
        __syncthreads();
        int tot = 0;
        #pragma unroll
        for (int w = 0; w < NT / 64; ++w) tot += s_red[w];
        if (tot == 0) s_cum[tid] = tid + 1;   // d=1 everywhere -> cum[t] = t+1
        __syncthreads();
    }

    // ---- per-frame phoneme index via branchless upper_bound ----
    const int last = s_cum[T - 1];
    if (tid < F) {
        int t = frame0 + tid;
        int idx = 0;                    // idx = #elements <= t (side='right')
        #pragma unroll
        for (int step = T / 2; step > 0; step >>= 1)
            if (s_cum[idx + step - 1] <= t) idx += step;
        if (idx > T - 1) idx = T - 1;   // clamp for safe gather
        s_idx[tid] = (t < last) ? idx : -1;
    }
    __syncthreads();

    // ---- copy F*CH float4 items; item order == contiguous output (coalesced) ----
    const size_t obase = ((size_t)b * TOUT + frame0) * CH;
    const size_t ibase = (size_t)b * T * CH;
    #pragma unroll 4
    for (int item = tid; item < F * CH; item += NT) {
        int f = item / CH;              // constant divisor -> magic multiply
        int c = item - f * CH;
        int j = s_idx[f];
        float4 v = make_float4(0.f, 0.f, 0.f, 0.f);
        if (j >= 0) v = xs4[ibase + (size_t)j * CH + c];
        out4[obase + item] = v;
    }
}

extern "C" void kernel_launch(void* const* d_in, const int* in_sizes, int n_in,
                              void* d_out, int out_size, void* d_ws, size_t ws_size,
                              hipStream_t stream) {
    const float* xs  = (const float*)d_in[0];
    const int*   dur = (const int*)d_in[1];
    float*       out = (float*)d_out;

    dim3 grid(TOUT / F, B);             // 32 x 32 = 1024 blocks
    k_lenreg<<<grid, NT, 0, stream>>>((const float4*)xs, dur, (float4*)out);
}